// Round 3
// baseline (525.897 us; speedup 1.0000x reference)
//
#include <hip/hip_runtime.h>

typedef __attribute__((ext_vector_type(8))) short short8;
typedef __attribute__((ext_vector_type(4))) float f32x4;
typedef __attribute__((ext_vector_type(2))) unsigned int u32x2;
typedef unsigned short u16;

static constexpr int BATCH = 8;
static constexpr int NDIM  = 2048;
static constexpr int MDIM  = 2048;
static constexpr int EDIM  = 1024;
static constexpr int BM    = 256;
static constexpr int BN    = 256;
static constexpr int BK    = 64;

#define BAR() do { asm volatile("" ::: "memory"); \
                   __builtin_amdgcn_s_barrier(); \
                   asm volatile("" ::: "memory"); } while (0)
#define WFENCE() asm volatile("s_waitcnt lgkmcnt(0)" ::: "memory")

// Fused fp32->bf16 256x256 8-phase GEMM.
// Staging: global fp32 -> v_cvt_pk_bf16_f32 -> swizzled ds_write_b64.
// LDS[r][16B-chunk c] holds global chunk (r, c ^ (r&7)).
// Buffer discipline (the R2 bug fix): ALL reads of a buffer's tile finish
// before ANY write to that buffer. Reads buf0: ph1-ph3. Writes buf0: ph4-ph7.
// Reads buf1: ph5-ph7(+ph8 MM regs). Writes buf1: ph8, next ph1-ph3.
// Every phase segment reads one buffer and writes only the other.
__global__ __launch_bounds__(512, 2)
void bmm_fused_kernel(const float* __restrict__ A, const float* __restrict__ B,
                      float* __restrict__ C) {
  __shared__ u16 sh[2][2][BM * BK];   // [buf][A=0/B=1][256 x 64] = 128 KiB

  const int tid  = threadIdx.x;
  const int lane = tid & 63;
  const int wave = tid >> 6;      // 0..7
  const int wr   = wave >> 2;     // 0..1
  const int wc   = wave & 3;      // 0..3
  const int quad = lane >> 4;
  const int ml   = lane & 15;

  // XCD-aware bijective swizzle: 512 blocks = 8 XCDs x 64; each XCD owns one
  // batch (64 tiles) -> A/B panel re-reads become L2-local.
  const int flat  = (int)blockIdx.x + 8 * (int)blockIdx.y + 64 * (int)blockIdx.z;
  const int nf    = (flat & 7) * 64 + (flat >> 3);
  const int batch = nf >> 6;
  const int trow  = (nf >> 3) & 7;
  const int tcol  = nf & 7;

  const float* Ab = A + (size_t)batch * NDIM * EDIM + (size_t)trow * BM * EDIM;
  const float* Bb = B + (size_t)batch * MDIM * EDIM + (size_t)tcol * BN * EDIM;

  // ---- staging addressing ----
  // half-tile h = rows h*128..h*128+127. Thread: rows rowb + j*32 (j=0..3),
  // fp32 cols colf..colf+3 -> 2 cvt_pk -> one ds_write_b64 (8B = half chunk).
  const int rowb = tid >> 4;                  // 0..31
  const int colf = (tid & 15) * 4;
  const int swzoff = ((((tid & 15) >> 1) ^ (rowb & 7)) << 3) | ((tid & 1) << 2);
  const float* pA = Ab + (size_t)rowb * EDIM + colf;
  const float* pB = Bb + (size_t)rowb * EDIM + colf;

  // ---- ds_read fragment addressing (swizzled; verified in R1) ----
  const int aBase = (wr * 128 + ml) * 64;
  const int bBase = (wc * 64 + ml) * 64;
  const int kc0 = ((quad    ) ^ (ml & 7)) * 8;
  const int kc1 = ((quad + 4) ^ (ml & 7)) * 8;

  short8 ar[4][2], br0[2][2], br1[2][2];
  f32x4 acc[8][4] = {};
  f32x4 s0v[4], s1v[4];               // two staging sets (distance-2 pipeline)

#define ISS(Sp, P, h, t) do {                                                  \
    const float* _p = (P) + (size_t)((h) * 128) * EDIM + (size_t)(t) * BK;     \
    Sp[0] = *(const f32x4*)(_p);                                               \
    Sp[1] = *(const f32x4*)(_p + (size_t)32 * EDIM);                           \
    Sp[2] = *(const f32x4*)(_p + (size_t)64 * EDIM);                           \
    Sp[3] = *(const f32x4*)(_p + (size_t)96 * EDIM);                           \
  } while (0)

#define WRT(Sp, buf, ab, h) do {                                               \
    _Pragma("unroll")                                                          \
    for (int _j = 0; _j < 4; ++_j) {                                           \
      unsigned _lo, _hi;                                                       \
      asm("v_cvt_pk_bf16_f32 %0, %1, %2"                                       \
          : "=v"(_lo) : "v"(Sp[_j][0]), "v"(Sp[_j][1]));                       \
      asm("v_cvt_pk_bf16_f32 %0, %1, %2"                                       \
          : "=v"(_hi) : "v"(Sp[_j][2]), "v"(Sp[_j][3]));                       \
      u32x2 _u; _u[0] = _lo; _u[1] = _hi;                                      \
      *(u32x2*)&sh[buf][ab][((h) * 128 + rowb + _j * 32) * 64 + swzoff] = _u;  \
    } } while (0)

#define LDA(buf, mh) do {                                                      \
    _Pragma("unroll")                                                          \
    for (int _q = 0; _q < 4; ++_q) {                                           \
      ar[_q][0] = *(const short8*)&sh[buf][0][aBase + (mh)*4096 + _q*1024 + kc0];\
      ar[_q][1] = *(const short8*)&sh[buf][0][aBase + (mh)*4096 + _q*1024 + kc1];\
    } } while (0)

#define LDB(dst, buf, nh) do {                                                 \
    _Pragma("unroll")                                                          \
    for (int _n = 0; _n < 2; ++_n) {                                           \
      dst[_n][0] = *(const short8*)&sh[buf][1][bBase + (nh)*2048 + _n*1024 + kc0];\
      dst[_n][1] = *(const short8*)&sh[buf][1][bBase + (nh)*2048 + _n*1024 + kc1];\
    } } while (0)

#define MM(mh, nh, BSRC) do {                                                  \
    __builtin_amdgcn_s_setprio(1);                                             \
    _Pragma("unroll")                                                          \
    for (int _q = 0; _q < 4; ++_q)                                             \
      _Pragma("unroll")                                                        \
      for (int _n = 0; _n < 2; ++_n)                                           \
        _Pragma("unroll")                                                      \
        for (int _ks = 0; _ks < 2; ++_ks)                                      \
          acc[(mh)*4 + _q][(nh)*2 + _n] = __builtin_amdgcn_mfma_f32_16x16x32_bf16(\
              ar[_q][_ks], BSRC[_n][_ks], acc[(mh)*4 + _q][(nh)*2 + _n], 0, 0, 0);\
    __builtin_amdgcn_s_setprio(0);                                             \
  } while (0)

  // ---- prologue: buf0 <- t0 (all), buf1.Ah0 <- t1.
  //      Loop invariant at ph1: s1v = t1.Ah1, s0v = t1.Bh0. ----
  ISS(s1v, pA, 0, 0);           // t0.Ah0
  ISS(s0v, pA, 1, 0);           // t0.Ah1
  WRT(s1v, 0, 0, 0);
  ISS(s1v, pB, 0, 0);           // t0.Bh0
  WRT(s0v, 0, 0, 1);
  ISS(s0v, pB, 1, 0);           // t0.Bh1
  WRT(s1v, 0, 1, 0);
  ISS(s1v, pA, 0, 1);           // t1.Ah0
  WRT(s0v, 0, 1, 1);
  ISS(s0v, pB, 0, 1);           // t1.Bh0 -> pending
  WRT(s1v, 1, 0, 0);            // b1.Ah0
  ISS(s1v, pA, 1, 1);           // t1.Ah1 -> pending
  WFENCE();
  BAR();

  // ---- main loop: tiles t0=2i (buf0), t1=2i+1 (buf1); prefetch p0=2i+2,
  //      p1=2i+3. Writes: ph1:b1.Ah1<-t1  ph2:b1.Bh0<-t1  ph3:b1.Bh1<-t1
  //      ph4:b0.Ah0<-p0  ph5:b0.Ah1<-p0  ph6:b0.Bh0<-p0  ph7:b0.Bh1<-p0
  //      ph8:b1.Ah0<-p1.  ISS at ph_k feeds WRT at ph_{k+2}. ----
#pragma unroll 1
  for (int i = 0; i < 7; ++i) {
    const int t1 = 2 * i + 1, p0 = 2 * i + 2, p1 = 2 * i + 3;
    // ph1
    LDA(0, 0); LDB(br0, 0, 0);
    WRT(s1v, 1, 0, 1);          // b1.Ah1 <- t1
    ISS(s1v, pB, 1, t1);        // t1.Bh1
    BAR(); MM(0, 0, br0); WFENCE(); BAR();
    // ph2
    LDB(br1, 0, 1);
    WRT(s0v, 1, 1, 0);          // b1.Bh0 <- t1
    ISS(s0v, pA, 0, p0);        // p0.Ah0
    BAR(); MM(0, 1, br1); WFENCE(); BAR();
    // ph3
    LDA(0, 1);
    WRT(s1v, 1, 1, 1);          // b1.Bh1 <- t1
    ISS(s1v, pA, 1, p0);        // p0.Ah1
    BAR(); MM(1, 1, br1); WFENCE(); BAR();
    // ph4 (no ds_reads; br0 still holds Bh0)
    WRT(s0v, 0, 0, 0);          // b0.Ah0 <- p0
    ISS(s0v, pB, 0, p0);        // p0.Bh0
    BAR(); MM(1, 0, br0); WFENCE(); BAR();
    // ph5
    LDA(1, 0); LDB(br0, 1, 0);
    WRT(s1v, 0, 0, 1);          // b0.Ah1 <- p0
    ISS(s1v, pB, 1, p0);        // p0.Bh1
    BAR(); MM(0, 0, br0); WFENCE(); BAR();
    // ph6
    LDB(br1, 1, 1);
    WRT(s0v, 0, 1, 0);          // b0.Bh0 <- p0
    ISS(s0v, pA, 0, p1);        // p1.Ah0
    BAR(); MM(0, 1, br1); WFENCE(); BAR();
    // ph7
    LDA(1, 1);
    WRT(s1v, 0, 1, 1);          // b0.Bh1 <- p0
    ISS(s1v, pA, 1, p1);        // p1.Ah1 -> pending
    BAR(); MM(1, 1, br1); WFENCE(); BAR();
    // ph8 (no ds_reads)
    WRT(s0v, 1, 0, 0);          // b1.Ah0 <- p1
    ISS(s0v, pB, 0, p1);        // p1.Bh0 -> pending
    BAR(); MM(1, 0, br0); WFENCE(); BAR();
  }

  // ---- epilogue: t14 (buf0), t15 (buf1). Entering: s1v=t15.Ah1, s0v=t15.Bh0.
  {
    // e1
    LDA(0, 0); LDB(br0, 0, 0);
    WRT(s1v, 1, 0, 1);          // b1.Ah1 <- t15
    ISS(s1v, pB, 1, 15);        // t15.Bh1
    BAR(); MM(0, 0, br0); WFENCE(); BAR();
    // e2
    LDB(br1, 0, 1);
    WRT(s0v, 1, 1, 0);          // b1.Bh0 <- t15
    BAR(); MM(0, 1, br1); WFENCE(); BAR();
    // e3
    LDA(0, 1);
    WRT(s1v, 1, 1, 1);          // b1.Bh1 <- t15
    BAR(); MM(1, 1, br1); WFENCE(); BAR();
    // e4 (register-only)
    MM(1, 0, br0);
    // e5
    LDA(1, 0); LDB(br0, 1, 0);
    BAR(); MM(0, 0, br0); BAR();
    // e6
    LDB(br1, 1, 1);
    BAR(); MM(0, 1, br1); BAR();
    // e7
    LDA(1, 1);
    BAR(); MM(1, 1, br1); BAR();
    // e8
    MM(1, 0, br0);
  }

  // ---- C write (identical mapping to verified R1) ----
  float* Cb = C + (size_t)batch * NDIM * MDIM
                + (size_t)(trow * BM + wr * 128 + quad * 4) * MDIM
                + (tcol * BN + wc * 64 + ml);
#pragma unroll
  for (int mi = 0; mi < 8; ++mi) {
#pragma unroll
    for (int ni = 0; ni < 4; ++ni) {
      float* cp = Cb + (size_t)(mi * 16) * MDIM + ni * 16;
#pragma unroll
      for (int r = 0; r < 4; ++r)
        cp[(size_t)r * MDIM] = acc[mi][ni][r];
    }
  }
#undef ISS
#undef WRT
#undef LDA
#undef LDB
#undef MM
}

extern "C" void kernel_launch(void* const* d_in, const int* in_sizes, int n_in,
                              void* d_out, int out_size, void* d_ws, size_t ws_size,
                              hipStream_t stream) {
  const float* A = (const float*)d_in[0];
  const float* B = (const float*)d_in[1];
  float*       C = (float*)d_out;
  (void)d_ws; (void)ws_size;  // workspace intentionally unused

  dim3 grid(MDIM / BN, NDIM / BM, BATCH);   // 8 x 8 x 8
  bmm_fused_kernel<<<grid, dim3(512), 0, stream>>>(A, B, C);
}

// Round 4
// 342.703 us; speedup vs baseline: 1.5346x; 1.5346x over previous
//
#include <hip/hip_runtime.h>

typedef __attribute__((ext_vector_type(8))) short short8;
typedef __attribute__((ext_vector_type(4))) float f32x4;
typedef __attribute__((ext_vector_type(2))) unsigned int u32x2;
typedef unsigned short u16;

static constexpr int BATCH = 8;
static constexpr int NDIM  = 2048;
static constexpr int MDIM  = 2048;
static constexpr int EDIM  = 1024;
static constexpr int BM    = 256;
static constexpr int BN    = 256;
static constexpr int BK    = 64;

#define BAR() do { asm volatile("" ::: "memory"); \
                   __builtin_amdgcn_s_barrier(); \
                   asm volatile("" ::: "memory"); } while (0)
#define WFENCE() asm volatile("s_waitcnt lgkmcnt(0)" ::: "memory")

// Fused fp32->bf16 256x256 8-phase GEMM, register-budget-safe version.
// Per-wave unified RF budget is 256 (8-wave block => 2 waves/SIMD of a
// 512-reg file). acc = 128 (AGPR side) => arch VGPR budget 128. R3 spilled
// (~436 MB scratch writes) because demand was ~140. This version drops the
// second B-fragment set (re-reads Bh0 at ph4/ph8) => demand ~105.
// Buffer discipline: EVERY phase reads exactly one buffer and ds_writes only
// the other. Reads b0: ph1-4, writes b1: ph1-4 (tile t1); reads b1: ph5-8,
// writes b0: ph5-8 (tile t0+2). ISS->WRT distance 2, sets X/Y alternate.
__global__ __launch_bounds__(512, 2)
void bmm_fused_kernel(const float* __restrict__ A, const float* __restrict__ B,
                      float* __restrict__ C) {
  __shared__ u16 sh[2][2][BM * BK];   // [buf][A=0/B=1][256 x 64] = 128 KiB

  const int tid  = threadIdx.x;
  const int lane = tid & 63;
  const int wave = tid >> 6;      // 0..7
  const int wr   = wave >> 2;     // 0..1
  const int wc   = wave & 3;      // 0..3
  const int quad = lane >> 4;
  const int ml   = lane & 15;

  // XCD-aware bijective swizzle: 512 blocks = 8 XCDs x 64; XCD x owns batch x.
  const int flat  = (int)blockIdx.x + 8 * (int)blockIdx.y + 64 * (int)blockIdx.z;
  const int nf    = (flat & 7) * 64 + (flat >> 3);
  const int batch = nf >> 6;
  const int trow  = (nf >> 3) & 7;
  const int tcol  = nf & 7;

  const float* Ab = A + (size_t)batch * NDIM * EDIM + (size_t)trow * BM * EDIM;
  const float* Bb = B + (size_t)batch * MDIM * EDIM + (size_t)tcol * BN * EDIM;

  // ---- staging addressing ----
  // half-tile h = rows h*128..h*128+127 of the 256x64 tile. Thread covers
  // rows rowb + j*32 (j=0..3), fp32 cols colf..colf+3 -> 2 cvt_pk -> one
  // ds_write_b64 (8 B). Swizzle: 16B-chunk c stored at c ^ (row&7);
  // row&7 == rowb&7 (j*32 = 0 mod 8).
  const int rowb = tid >> 4;                  // 0..31
  const int colf = (tid & 15) * 4;
  const int swzoff = ((((tid & 15) >> 1) ^ (rowb & 7)) << 3) | ((tid & 1) << 2);
  const float* pA = Ab + (size_t)rowb * EDIM + colf;
  const float* pB = Bb + (size_t)rowb * EDIM + colf;

  // ---- ds_read fragment addressing (swizzled; verified R1/R3) ----
  const int aBase = (wr * 128 + ml) * 64;
  const int bBase = (wc * 64 + ml) * 64;
  const int kc0 = ((quad    ) ^ (ml & 7)) * 8;
  const int kc1 = ((quad + 4) ^ (ml & 7)) * 8;

  short8 ar[4][2], br[2][2];
  f32x4 acc[8][4] = {};
  f32x4 X[4], Y[4];               // two staging sets, distance-2 pipeline

#define ISS(Sp, P, h, t) do {                                                  \
    const float* _p = (P) + (size_t)((h) * 128) * EDIM + (size_t)(t) * BK;     \
    Sp[0] = *(const f32x4*)(_p);                                               \
    Sp[1] = *(const f32x4*)(_p + (size_t)32 * EDIM);                           \
    Sp[2] = *(const f32x4*)(_p + (size_t)64 * EDIM);                           \
    Sp[3] = *(const f32x4*)(_p + (size_t)96 * EDIM);                           \
  } while (0)

#define WRT(Sp, buf, ab, h) do {                                               \
    _Pragma("unroll")                                                          \
    for (int _j = 0; _j < 4; ++_j) {                                           \
      unsigned _lo, _hi;                                                       \
      asm("v_cvt_pk_bf16_f32 %0, %1, %2"                                       \
          : "=v"(_lo) : "v"(Sp[_j][0]), "v"(Sp[_j][1]));                       \
      asm("v_cvt_pk_bf16_f32 %0, %1, %2"                                       \
          : "=v"(_hi) : "v"(Sp[_j][2]), "v"(Sp[_j][3]));                       \
      u32x2 _u; _u[0] = _lo; _u[1] = _hi;                                      \
      *(u32x2*)&sh[buf][ab][((h) * 128 + rowb + _j * 32) * 64 + swzoff] = _u;  \
    } } while (0)

#define LDA(buf, mh) do {                                                      \
    _Pragma("unroll")                                                          \
    for (int _q = 0; _q < 4; ++_q) {                                           \
      ar[_q][0] = *(const short8*)&sh[buf][0][aBase + (mh)*4096 + _q*1024 + kc0];\
      ar[_q][1] = *(const short8*)&sh[buf][0][aBase + (mh)*4096 + _q*1024 + kc1];\
    } } while (0)

#define LDB(buf, nh) do {                                                      \
    _Pragma("unroll")                                                          \
    for (int _n = 0; _n < 2; ++_n) {                                           \
      br[_n][0] = *(const short8*)&sh[buf][1][bBase + (nh)*2048 + _n*1024 + kc0];\
      br[_n][1] = *(const short8*)&sh[buf][1][bBase + (nh)*2048 + _n*1024 + kc1];\
    } } while (0)

#define MM(mh, nh) do {                                                        \
    __builtin_amdgcn_s_setprio(1);                                             \
    _Pragma("unroll")                                                          \
    for (int _q = 0; _q < 4; ++_q)                                             \
      _Pragma("unroll")                                                        \
      for (int _n = 0; _n < 2; ++_n)                                           \
        _Pragma("unroll")                                                      \
        for (int _ks = 0; _ks < 2; ++_ks)                                      \
          acc[(mh)*4 + _q][(nh)*2 + _n] = __builtin_amdgcn_mfma_f32_16x16x32_bf16(\
              ar[_q][_ks], br[_n][_ks], acc[(mh)*4 + _q][(nh)*2 + _n], 0, 0, 0);\
    __builtin_amdgcn_s_setprio(0);                                             \
  } while (0)

  // ---- prologue: buf0 <- tile0; pending X = t1.Ah0, Y = t1.Ah1 ----
  ISS(X, pA, 0, 0);             // t0.Ah0
  ISS(Y, pA, 1, 0);             // t0.Ah1
  WRT(X, 0, 0, 0);              // b0.Ah0
  ISS(X, pB, 0, 0);             // t0.Bh0
  WRT(Y, 0, 0, 1);              // b0.Ah1
  ISS(Y, pB, 1, 0);             // t0.Bh1
  WRT(X, 0, 1, 0);              // b0.Bh0
  ISS(X, pA, 0, 1);             // t1.Ah0 -> pending (loop ph1)
  WRT(Y, 0, 1, 1);              // b0.Bh1
  ISS(Y, pA, 1, 1);             // t1.Ah1 -> pending (loop ph2)
  WFENCE();
  BAR();

  // ---- main loop: t0=2i (buf0), t1=2i+1 (buf1); p0=2i+2, p1=2i+3.
  // WRT schedule: ph1:b1.Ah0<-t1  ph2:b1.Ah1<-t1  ph3:b1.Bh0<-t1  ph4:b1.Bh1<-t1
  //               ph5:b0.Ah0<-p0  ph6:b0.Ah1<-p0  ph7:b0.Bh0<-p0  ph8:b0.Bh1<-p0
  // ISS at ph k feeds WRT at ph k+2 (X odd phases, Y even phases).
#pragma unroll 1
  for (int i = 0; i < 7; ++i) {
    const int t1 = 2 * i + 1, p0 = 2 * i + 2, p1 = 2 * i + 3;
    // ph1: reads b0, writes b1
    LDA(0, 0); LDB(0, 0);
    WRT(X, 1, 0, 0);            // b1.Ah0 <- t1
    ISS(X, pB, 0, t1);
    BAR(); MM(0, 0); WFENCE(); BAR();
    // ph2
    LDB(0, 1);
    WRT(Y, 1, 0, 1);            // b1.Ah1 <- t1
    ISS(Y, pB, 1, t1);
    BAR(); MM(0, 1); WFENCE(); BAR();
    // ph3
    LDA(0, 1);
    WRT(X, 1, 1, 0);            // b1.Bh0 <- t1
    ISS(X, pA, 0, p0);
    BAR(); MM(1, 1); WFENCE(); BAR();
    // ph4: re-read t0.Bh0 (b0 untouched since last iter); writes b1
    LDB(0, 0);
    WRT(Y, 1, 1, 1);            // b1.Bh1 <- t1
    ISS(Y, pA, 1, p0);
    BAR(); MM(1, 0); WFENCE(); BAR();
    // ph5: reads b1 (t1 complete), writes b0
    LDA(1, 0); LDB(1, 0);
    WRT(X, 0, 0, 0);            // b0.Ah0 <- p0
    ISS(X, pB, 0, p0);
    BAR(); MM(0, 0); WFENCE(); BAR();
    // ph6
    LDB(1, 1);
    WRT(Y, 0, 0, 1);            // b0.Ah1 <- p0
    ISS(Y, pB, 1, p0);
    BAR(); MM(0, 1); WFENCE(); BAR();
    // ph7
    LDA(1, 1);
    WRT(X, 0, 1, 0);            // b0.Bh0 <- p0
    ISS(X, pA, 0, p1);          // -> pending
    BAR(); MM(1, 1); WFENCE(); BAR();
    // ph8: re-read t1.Bh0 (written ph3, fenced); writes b0
    LDB(1, 0);
    WRT(Y, 0, 1, 1);            // b0.Bh1 <- p0
    ISS(Y, pA, 1, p1);          // -> pending
    BAR(); MM(1, 0); WFENCE(); BAR();
  }

  // ---- epilogue: t14 (buf0), t15 (buf1). Entering: X=t15.Ah0, Y=t15.Ah1 ----
  {
    // e1
    LDA(0, 0); LDB(0, 0);
    WRT(X, 1, 0, 0);            // b1.Ah0 <- t15
    ISS(X, pB, 0, 15);
    BAR(); MM(0, 0); WFENCE(); BAR();
    // e2
    LDB(0, 1);
    WRT(Y, 1, 0, 1);            // b1.Ah1 <- t15
    ISS(Y, pB, 1, 15);
    BAR(); MM(0, 1); WFENCE(); BAR();
    // e3
    LDA(0, 1);
    WRT(X, 1, 1, 0);            // b1.Bh0 <- t15
    BAR(); MM(1, 1); WFENCE(); BAR();
    // e4
    LDB(0, 0);
    WRT(Y, 1, 1, 1);            // b1.Bh1 <- t15
    BAR(); MM(1, 0); WFENCE(); BAR();
    // e5: reads b1 (t15 complete)
    LDA(1, 0); LDB(1, 0);
    BAR(); MM(0, 0); BAR();
    // e6
    LDB(1, 1);
    BAR(); MM(0, 1); BAR();
    // e7
    LDA(1, 1);
    BAR(); MM(1, 1); BAR();
    // e8 (own-wave ds_read only; b1.Bh0 published at e3)
    LDB(1, 0);
    MM(1, 0);
  }

  // ---- C write (verified mapping) ----
  float* Cb = C + (size_t)batch * NDIM * MDIM
                + (size_t)(trow * BM + wr * 128 + quad * 4) * MDIM
                + (tcol * BN + wc * 64 + ml);
#pragma unroll
  for (int mi = 0; mi < 8; ++mi) {
#pragma unroll
    for (int ni = 0; ni < 4; ++ni) {
      float* cp = Cb + (size_t)(mi * 16) * MDIM + ni * 16;
#pragma unroll
      for (int r = 0; r < 4; ++r)
        cp[(size_t)r * MDIM] = acc[mi][ni][r];
    }
  }
#undef ISS
#undef WRT
#undef LDA
#undef LDB
#undef MM
}

extern "C" void kernel_launch(void* const* d_in, const int* in_sizes, int n_in,
                              void* d_out, int out_size, void* d_ws, size_t ws_size,
                              hipStream_t stream) {
  const float* A = (const float*)d_in[0];
  const float* B = (const float*)d_in[1];
  float*       C = (float*)d_out;
  (void)d_ws; (void)ws_size;  // workspace intentionally unused

  dim3 grid(MDIM / BN, NDIM / BM, BATCH);   // 8 x 8 x 8
  bmm_fused_kernel<<<grid, dim3(512), 0, stream>>>(A, B, C);
}

// Round 5
// 334.093 us; speedup vs baseline: 1.5741x; 1.0258x over previous
//
#include <hip/hip_runtime.h>

typedef __attribute__((ext_vector_type(8))) short short8;
typedef __attribute__((ext_vector_type(4))) float f32x4;
typedef __attribute__((ext_vector_type(2))) unsigned int u32x2;
typedef unsigned short u16;

static constexpr int BATCH = 8;
static constexpr int NDIM  = 2048;
static constexpr int MDIM  = 2048;
static constexpr int EDIM  = 1024;
static constexpr int BM    = 128;
static constexpr int BN    = 128;
static constexpr int BK    = 64;

#define BAR() do { asm volatile("" ::: "memory"); \
                   __builtin_amdgcn_s_barrier(); \
                   asm volatile("" ::: "memory"); } while (0)
#define WFENCE() asm volatile("s_waitcnt lgkmcnt(0)" ::: "memory")

// Fused fp32->bf16 128x128 GEMM, 4 waves (wave tile 64x64 -> acc=64 regs).
// R3/R4 lesson: 8-wave blocks cap unified regs at 256/wave; acc=128 left only
// 128 arch VGPRs -> spill (100-436 MB scratch). Here acc=64 => demand ~200/256.
// LDS 64 KB => 2 independent blocks/CU (mutual latency hiding).
// Buffer discipline (R4-proven): phases 1-4 read buf0 / write buf1 (tile t1),
// phases 5-8 read buf1 / write buf0 (tile t0+2). Single staging set X,
// distance-1 (WRT consumes X, then ISS refills it in the same phase).
__global__ __launch_bounds__(256, 2)
void bmm_fused_kernel(const float* __restrict__ A, const float* __restrict__ B,
                      float* __restrict__ C) {
  __shared__ u16 sh[2][2][BM * BK];   // [buf][A=0/B=1][128 x 64] = 64 KiB

  const int tid  = threadIdx.x;
  const int lane = tid & 63;
  const int wave = tid >> 6;      // 0..3
  const int quad = lane >> 4;
  const int ml   = lane & 15;
  const int wrow = (wave >> 1) * 64;
  const int wcol = (wave & 1) * 64;

  // XCD-bijective swizzle: 2048 blocks = 8 XCDs x 256; XCD x owns batch x
  // (16x16 tiles), tcol fastest -> A-panel reuse is XCD-local.
  const int flat  = (int)blockIdx.x + 16 * (int)blockIdx.y + 256 * (int)blockIdx.z;
  const int nf    = (flat & 7) * 256 + (flat >> 3);
  const int batch = nf >> 8;
  const int trow  = (nf >> 4) & 15;
  const int tcol  = nf & 15;

  const float* Ab = A + (size_t)batch * NDIM * EDIM + (size_t)trow * BM * EDIM;
  const float* Bb = B + (size_t)batch * MDIM * EDIM + (size_t)tcol * BN * EDIM;

  // ---- staging addressing ----
  // unit = 64 rows x 64 cols. Thread: rows rowb + j*16 (j=0..3), fp32 cols
  // colf..colf+3 -> 2 cvt_pk -> one ds_write_b64. Swizzle (R4-verified):
  // 16B chunk c of row r stored at chunk c ^ (r&7); r&7 == rowb&7.
  const int rowb = tid >> 4;                  // 0..15
  const int ci   = tid & 15;
  const int colf = ci * 4;
  const int swzoff = (((ci >> 1) ^ (rowb & 7)) << 3) | ((ci & 1) << 2);
  const float* pA = Ab + (size_t)rowb * EDIM + colf;
  const float* pB = Bb + (size_t)rowb * EDIM + colf;

  // ---- ds_read fragment addressing (swizzled; R1/R4-verified) ----
  const int aOff = (wrow + ml) * 64;
  const int bOff = (wcol + ml) * 64;
  const int kc0 = ((quad    ) ^ (ml & 7)) * 8;
  const int kc1 = ((quad + 4) ^ (ml & 7)) * 8;

  short8 ar[2][2], br[2][2];
  f32x4 acc[4][4] = {};
  f32x4 X[4];                     // single staging set, distance-1

#define ISS(P, u, t) do {                                                      \
    const float* _p = (P) + (size_t)((u) * 64) * EDIM + (size_t)(t) * BK;      \
    X[0] = *(const f32x4*)(_p);                                                \
    X[1] = *(const f32x4*)(_p + (size_t)16 * EDIM);                            \
    X[2] = *(const f32x4*)(_p + (size_t)32 * EDIM);                            \
    X[3] = *(const f32x4*)(_p + (size_t)48 * EDIM);                            \
  } while (0)

#define WRT(buf, ab, u) do {                                                   \
    _Pragma("unroll")                                                          \
    for (int _j = 0; _j < 4; ++_j) {                                           \
      unsigned _lo, _hi;                                                       \
      asm("v_cvt_pk_bf16_f32 %0, %1, %2"                                       \
          : "=v"(_lo) : "v"(X[_j][0]), "v"(X[_j][1]));                         \
      asm("v_cvt_pk_bf16_f32 %0, %1, %2"                                       \
          : "=v"(_hi) : "v"(X[_j][2]), "v"(X[_j][3]));                         \
      u32x2 _u; _u[0] = _lo; _u[1] = _hi;                                      \
      *(u32x2*)&sh[buf][ab][((u) * 64 + rowb + _j * 16) * 64 + swzoff] = _u;   \
    } } while (0)

#define LDA(buf, mh) do {                                                      \
    _Pragma("unroll")                                                          \
    for (int _s = 0; _s < 2; ++_s) {                                           \
      ar[_s][0] = *(const short8*)&sh[buf][0][aOff + ((mh)*32 + _s*16)*64 + kc0];\
      ar[_s][1] = *(const short8*)&sh[buf][0][aOff + ((mh)*32 + _s*16)*64 + kc1];\
    } } while (0)

#define LDB(buf, nh) do {                                                      \
    _Pragma("unroll")                                                          \
    for (int _s = 0; _s < 2; ++_s) {                                           \
      br[_s][0] = *(const short8*)&sh[buf][1][bOff + ((nh)*32 + _s*16)*64 + kc0];\
      br[_s][1] = *(const short8*)&sh[buf][1][bOff + ((nh)*32 + _s*16)*64 + kc1];\
    } } while (0)

#define MM(mh, nh) do {                                                        \
    __builtin_amdgcn_s_setprio(1);                                             \
    _Pragma("unroll")                                                          \
    for (int _sa = 0; _sa < 2; ++_sa)                                          \
      _Pragma("unroll")                                                        \
      for (int _sb = 0; _sb < 2; ++_sb)                                        \
        _Pragma("unroll")                                                      \
        for (int _ks = 0; _ks < 2; ++_ks)                                      \
          acc[(mh)*2 + _sa][(nh)*2 + _sb] = __builtin_amdgcn_mfma_f32_16x16x32_bf16(\
              ar[_sa][_ks], br[_sb][_ks], acc[(mh)*2 + _sa][(nh)*2 + _sb], 0, 0, 0);\
    __builtin_amdgcn_s_setprio(0);                                             \
  } while (0)

  // ---- prologue: buf0 <- tile0 (A0,A1,B0,B1); X <- t1.A0 pending ----
  ISS(pA, 0, 0); WRT(0, 0, 0);
  ISS(pA, 1, 0); WRT(0, 0, 1);
  ISS(pB, 0, 0); WRT(0, 1, 0);
  ISS(pB, 1, 0); WRT(0, 1, 1);
  ISS(pA, 0, 1);                // t1.A0 -> pending
  WFENCE();
  BAR();

  // ---- main loop: i covers K-tiles t0=2i (buf0) and t1=2i+1 (buf1).
  // WRT targets: ph1-4 -> buf1 {A0,A1,B0,B1} <- t1; ph5-8 -> buf0 <- tp0.
  // ISS at phase k refills X for WRT at phase k+1. Clamped prefetch at tail
  // (writes land in the buffer that is never read again -> harmless).
#pragma unroll 1
  for (int i = 0; i < 8; ++i) {
    const int t1  = 2 * i + 1;
    const int tp0 = (2 * i + 2 < 15) ? 2 * i + 2 : 15;
    const int tp1 = (2 * i + 3 < 15) ? 2 * i + 3 : 15;
    // ph1: read b0, write b1.A0
    LDA(0, 0); LDB(0, 0);
    WRT(1, 0, 0); ISS(pA, 1, t1);
    BAR(); MM(0, 0); WFENCE(); BAR();
    // ph2: write b1.A1
    LDB(0, 1);
    WRT(1, 0, 1); ISS(pB, 0, t1);
    BAR(); MM(0, 1); WFENCE(); BAR();
    // ph3: write b1.B0
    LDA(0, 1);
    WRT(1, 1, 0); ISS(pB, 1, t1);
    BAR(); MM(1, 1); WFENCE(); BAR();
    // ph4: re-read b0.B0 (b0 untouched in ph1-4); write b1.B1
    LDB(0, 0);
    WRT(1, 1, 1); ISS(pA, 0, tp0);
    BAR(); MM(1, 0); WFENCE(); BAR();
    // ph5: read b1 (t1 complete, fenced), write b0.A0 <- tp0
    LDA(1, 0); LDB(1, 0);
    WRT(0, 0, 0); ISS(pA, 1, tp0);
    BAR(); MM(0, 0); WFENCE(); BAR();
    // ph6
    LDB(1, 1);
    WRT(0, 0, 1); ISS(pB, 0, tp0);
    BAR(); MM(0, 1); WFENCE(); BAR();
    // ph7
    LDA(1, 1);
    WRT(0, 1, 0); ISS(pB, 1, tp0);
    BAR(); MM(1, 1); WFENCE(); BAR();
    // ph8: re-read b1.B0 (written ph3, fenced)
    LDB(1, 0);
    WRT(0, 1, 1); ISS(pA, 0, tp1);
    BAR(); MM(1, 0); WFENCE(); BAR();
  }

  // ---- C write (verified mapping: row = quad*4 + r, col = ml) ----
  float* Cb = C + (size_t)batch * NDIM * MDIM
                + (size_t)(trow * BM + wrow + quad * 4) * MDIM
                + (tcol * BN + wcol + ml);
#pragma unroll
  for (int mi = 0; mi < 4; ++mi) {
#pragma unroll
    for (int ni = 0; ni < 4; ++ni) {
      float* cp = Cb + (size_t)(mi * 16) * MDIM + ni * 16;
#pragma unroll
      for (int r = 0; r < 4; ++r)
        cp[(size_t)r * MDIM] = acc[mi][ni][r];
    }
  }
#undef ISS
#undef WRT
#undef LDA
#undef LDB
#undef MM
}

extern "C" void kernel_launch(void* const* d_in, const int* in_sizes, int n_in,
                              void* d_out, int out_size, void* d_ws, size_t ws_size,
                              hipStream_t stream) {
  const float* A = (const float*)d_in[0];
  const float* B = (const float*)d_in[1];
  float*       C = (float*)d_out;
  (void)d_ws; (void)ws_size;  // workspace intentionally unused

  dim3 grid(MDIM / BN, NDIM / BM, BATCH);   // 16 x 16 x 8 = 2048
  bmm_fused_kernel<<<grid, dim3(256), 0, stream>>>(A, B, C);
}

// Round 6
// 317.835 us; speedup vs baseline: 1.6546x; 1.0512x over previous
//
#include <hip/hip_runtime.h>

typedef __attribute__((ext_vector_type(8))) short short8;
typedef __attribute__((ext_vector_type(4))) float f32x4;
typedef __attribute__((ext_vector_type(2))) unsigned int u32x2;
typedef unsigned short u16;

static constexpr int BATCH = 8;
static constexpr int NDIM  = 2048;
static constexpr int MDIM  = 2048;
static constexpr int EDIM  = 1024;
static constexpr int BM    = 128;
static constexpr int BN    = 128;
static constexpr int BK    = 64;

#define BAR() do { asm volatile("" ::: "memory"); \
                   __builtin_amdgcn_s_barrier(); \
                   asm volatile("" ::: "memory"); } while (0)
#define WFENCE() asm volatile("s_waitcnt lgkmcnt(0)" ::: "memory")

// Fused fp32->bf16 128x128 GEMM, 4 waves, 2 blocks/CU, coarse 2-phase K-tiles.
// R5 post-mortem: 128 barrier-phases/block with distance-1 staging exposed the
// full global-load latency every phase (1750 cyc/phase for 40 cyc of MFMA).
// R6: 2 phases per K-tile (16 MFMA each), ONE barrier per phase (reads and
// ds_writes always hit opposite LDS buffers), 4 staging sets with ISS->WRT
// distance of 2 phases, WRT after the MFMA burst so vmcnt waits overlap the
// matrix pipe. Steady state per phase of tile u: read buf u&1, ds_write tile
// u+1's units into buf (u+1)&1, ISS tile u+2's units.
__global__ __launch_bounds__(256, 2)
void bmm_fused_kernel(const float* __restrict__ A, const float* __restrict__ B,
                      float* __restrict__ C) {
  __shared__ u16 sh[2][2][BM * BK];   // [buf][A=0/B=1][128 x 64] = 64 KiB

  const int tid  = threadIdx.x;
  const int lane = tid & 63;
  const int wave = tid >> 6;      // 0..3
  const int quad = lane >> 4;
  const int ml   = lane & 15;
  const int wrow = (wave >> 1) * 64;
  const int wcol = (wave & 1) * 64;

  // XCD-bijective swizzle: 2048 blocks = 8 XCDs x 256; XCD x owns batch x.
  const int flat  = (int)blockIdx.x + 16 * (int)blockIdx.y + 256 * (int)blockIdx.z;
  const int nf    = (flat & 7) * 256 + (flat >> 3);
  const int batch = nf >> 8;
  const int trow  = (nf >> 4) & 15;
  const int tcol  = nf & 15;

  const float* Ab = A + (size_t)batch * NDIM * EDIM + (size_t)trow * BM * EDIM;
  const float* Bb = B + (size_t)batch * MDIM * EDIM + (size_t)tcol * BN * EDIM;

  // ---- staging addressing (R4/R5-verified) ----
  // unit = 64 rows x 64 cols. Thread: rows rowb + j*16 (j=0..3), fp32 cols
  // colf..colf+3 -> 2 cvt_pk -> one ds_write_b64. Swizzle: 16B chunk c of
  // row r stored at chunk c ^ (r&7); r&7 == rowb&7.
  const int rowb = tid >> 4;                  // 0..15
  const int ci   = tid & 15;
  const int colf = ci * 4;
  const int swzoff = (((ci >> 1) ^ (rowb & 7)) << 3) | ((ci & 1) << 2);
  const float* pA = Ab + (size_t)rowb * EDIM + colf;
  const float* pB = Bb + (size_t)rowb * EDIM + colf;

  // ---- ds_read fragment addressing (swizzled; R1/R4/R5-verified) ----
  const int aOff = (wrow + ml) * 64;
  const int bOff = (wcol + ml) * 64;
  const int kc0 = ((quad    ) ^ (ml & 7)) * 8;
  const int kc1 = ((quad + 4) ^ (ml & 7)) * 8;

  short8 ar[2][2], br[4][2];
  f32x4 acc[4][4] = {};
  f32x4 SA0[4], SA1[4], SB0[4], SB1[4];   // 4 staging sets, distance-2

#define ISS(Sp, P, u, t) do {                                                  \
    const float* _p = (P) + (size_t)((u) * 64) * EDIM + (size_t)(t) * BK;      \
    Sp[0] = *(const f32x4*)(_p);                                               \
    Sp[1] = *(const f32x4*)(_p + (size_t)16 * EDIM);                           \
    Sp[2] = *(const f32x4*)(_p + (size_t)32 * EDIM);                           \
    Sp[3] = *(const f32x4*)(_p + (size_t)48 * EDIM);                           \
  } while (0)

#define WRT(Sp, buf, ab, u) do {                                               \
    _Pragma("unroll")                                                          \
    for (int _j = 0; _j < 4; ++_j) {                                           \
      unsigned _lo, _hi;                                                       \
      asm("v_cvt_pk_bf16_f32 %0, %1, %2"                                       \
          : "=v"(_lo) : "v"(Sp[_j][0]), "v"(Sp[_j][1]));                       \
      asm("v_cvt_pk_bf16_f32 %0, %1, %2"                                       \
          : "=v"(_hi) : "v"(Sp[_j][2]), "v"(Sp[_j][3]));                       \
      u32x2 _u; _u[0] = _lo; _u[1] = _hi;                                      \
      *(u32x2*)&sh[buf][ab][((u) * 64 + rowb + _j * 16) * 64 + swzoff] = _u;   \
    } } while (0)

#define LDA(buf, mh) do {                                                      \
    _Pragma("unroll")                                                          \
    for (int _s = 0; _s < 2; ++_s) {                                           \
      ar[_s][0] = *(const short8*)&sh[buf][0][aOff + ((mh)*32 + _s*16)*64 + kc0];\
      ar[_s][1] = *(const short8*)&sh[buf][0][aOff + ((mh)*32 + _s*16)*64 + kc1];\
    } } while (0)

#define LDBALL(buf) do {                                                       \
    _Pragma("unroll")                                                          \
    for (int _n = 0; _n < 4; ++_n) {                                           \
      br[_n][0] = *(const short8*)&sh[buf][1][bOff + _n*1024 + kc0];           \
      br[_n][1] = *(const short8*)&sh[buf][1][bOff + _n*1024 + kc1];           \
    } } while (0)

  // 16 MFMA: A-half mh (rows mh*32..mh*32+31) x all 64 cols x K=64
#define MM2(mh) do {                                                           \
    __builtin_amdgcn_s_setprio(1);                                             \
    _Pragma("unroll")                                                          \
    for (int _sa = 0; _sa < 2; ++_sa)                                          \
      _Pragma("unroll")                                                        \
      for (int _n = 0; _n < 4; ++_n)                                           \
        _Pragma("unroll")                                                      \
        for (int _ks = 0; _ks < 2; ++_ks)                                      \
          acc[(mh)*2 + _sa][_n] = __builtin_amdgcn_mfma_f32_16x16x32_bf16(     \
              ar[_sa][_ks], br[_n][_ks], acc[(mh)*2 + _sa][_n], 0, 0, 0);      \
    __builtin_amdgcn_s_setprio(0);                                             \
  } while (0)

  // ---- prologue: buf0 <- tile0 (direct); sets <- tile1 (pending) ----
  ISS(SA0, pA, 0, 0); ISS(SA1, pA, 1, 0); ISS(SB0, pB, 0, 0); ISS(SB1, pB, 1, 0);
  WRT(SA0, 0, 0, 0);  WRT(SA1, 0, 0, 1);  WRT(SB0, 0, 1, 0);  WRT(SB1, 0, 1, 1);
  ISS(SA0, pA, 0, 1); ISS(SA1, pA, 1, 1); ISS(SB0, pB, 0, 1); ISS(SB1, pB, 1, 1);
  WFENCE();
  BAR();

  // ---- main loop: tile u read from buf u&1; write tile u+1 -> buf (u+1)&1;
  //      ISS tile u+2 (clamped). Phase A: mh=0 (12 ds_reads, 16 MFMA);
  //      phase B: mh=1 (4 ds_reads, 16 MFMA). One barrier per phase. ----
#pragma unroll 1
  for (int u = 0; u < 16; ++u) {
    const int b  = u & 1;
    const int w  = b ^ 1;
    const int tp = (u < 14) ? u + 2 : 15;
    // phase A
    LDA(b, 0); LDBALL(b);
    MM2(0);
    __builtin_amdgcn_sched_barrier(0);   // keep MFMA burst ahead of vmcnt wait
    WRT(SA0, w, 0, 0); WRT(SA1, w, 0, 1);
    ISS(SA0, pA, 0, tp); ISS(SA1, pA, 1, tp);
    WFENCE(); BAR();
    // phase B
    LDA(b, 1);
    MM2(1);
    __builtin_amdgcn_sched_barrier(0);
    WRT(SB0, w, 1, 0); WRT(SB1, w, 1, 1);
    ISS(SB0, pB, 0, tp); ISS(SB1, pB, 1, tp);
    WFENCE(); BAR();
  }

  // ---- C write (verified mapping: row = quad*4 + r, col = ml) ----
  float* Cb = C + (size_t)batch * NDIM * MDIM
                + (size_t)(trow * BM + wrow + quad * 4) * MDIM
                + (tcol * BN + wcol + ml);
#pragma unroll
  for (int mi = 0; mi < 4; ++mi) {
#pragma unroll
    for (int ni = 0; ni < 4; ++ni) {
      float* cp = Cb + (size_t)(mi * 16) * MDIM + ni * 16;
#pragma unroll
      for (int r = 0; r < 4; ++r)
        cp[(size_t)r * MDIM] = acc[mi][ni][r];
    }
  }
#undef ISS
#undef WRT
#undef LDA
#undef LDBALL
#undef MM2
}

extern "C" void kernel_launch(void* const* d_in, const int* in_sizes, int n_in,
                              void* d_out, int out_size, void* d_ws, size_t ws_size,
                              hipStream_t stream) {
  const float* A = (const float*)d_in[0];
  const float* B = (const float*)d_in[1];
  float*       C = (float*)d_out;
  (void)d_ws; (void)ws_size;

  dim3 grid(MDIM / BN, NDIM / BM, BATCH);   // 16 x 16 x 8 = 2048
  bmm_fused_kernel<<<grid, dim3(256), 0, stream>>>(A, B, C);
}